// Round 14
// baseline (197.526 us; speedup 1.0000x reference)
//
#include <hip/hip_runtime.h>
#include <hip/hip_bf16.h>
#include <cstdint>
#include <cstddef>

typedef unsigned short u16;
typedef short bf16x8 __attribute__((ext_vector_type(8)));
typedef short bf16x4 __attribute__((ext_vector_type(4)));
typedef unsigned short u16x8 __attribute__((ext_vector_type(8)));
typedef unsigned short u16x4 __attribute__((ext_vector_type(4)));
typedef float f32x4 __attribute__((ext_vector_type(4)));

#define S_LEN 2048
#define BATCH 2
#define DM 1024
#define NHEAD 16
#define HDIM 64
#define MROWS (S_LEN * BATCH)  // 4096
#define LOG2E 1.44269504088896340736f
#define KSPLIT 2
#define SPAN (S_LEN / KSPLIT)  // 1024 keys per split-block
#define NROWS (NHEAD * BATCH * S_LEN)  // 65536 (hb, q) rows

__device__ __forceinline__ u16 f32_to_bf16(float f) {
  union { float f; uint32_t u; } v; v.f = f;
  uint32_t u = v.u;
  u += 0x7FFFu + ((u >> 16) & 1u);  // RNE
  return (u16)(u >> 16);
}
__device__ __forceinline__ u16 cvt_bf16(float f) {
  __hip_bfloat16 h = __float2bfloat16(f);
  return *reinterpret_cast<u16*>(&h);
}
__device__ __forceinline__ float bf2f(u16 x) {
  union { float f; uint32_t u; } v; v.u = ((uint32_t)x) << 16; return v.f;
}

__device__ __forceinline__ void gload_lds16(const void* g, void* l) {
  __builtin_amdgcn_global_load_lds(
      (const __attribute__((address_space(1))) void*)g,
      (__attribute__((address_space(3))) void*)l, 16, 0, 0);
}

// hardware transpose read: 4 bf16 per lane
__device__ __forceinline__ bf16x4 tr_read(const void* lp) {
  bf16x4 d;
  auto p = (const __attribute__((address_space(3))) short*)lp;
  asm volatile("ds_read_b64_tr_b16 %0, %1" : "=v"(d) : "v"(p));
  return d;
}

#if __has_builtin(__builtin_amdgcn_mfma_f32_16x16x16_bf16)
#define MFMA16(a, b, c) __builtin_amdgcn_mfma_f32_16x16x16_bf16(a, b, c, 0, 0, 0)
#elif __has_builtin(__builtin_amdgcn_mfma_f32_16x16x16bf16_1k)
#define MFMA16(a, b, c) __builtin_amdgcn_mfma_f32_16x16x16bf16_1k(a, b, c, 0, 0, 0)
#else
__device__ __forceinline__ f32x4 mfma16_asm(bf16x4 a, bf16x4 b, f32x4 c) {
  f32x4 d;
  asm volatile("v_mfma_f32_16x16x16_bf16 %0, %1, %2, %3\n\ts_nop 7\n\ts_nop 7"
               : "=&v"(d) : "v"(a), "v"(b), "v"(c));
  return d;
}
#define MFMA16(a, b, c) mfma16_asm(a, b, c)
#endif

// ---------------- fused fp32 -> bf16 casts (4 tensors, per-tensor scale) -------
__global__ void cast4_f32_bf16(const float* __restrict__ s0, u16* __restrict__ d0,
                               const float* __restrict__ s1, u16* __restrict__ d1,
                               const float* __restrict__ s2, u16* __restrict__ d2,
                               const float* __restrict__ s3, u16* __restrict__ d3,
                               float4 scales, int n8) {
  const int which = blockIdx.y;
  const float* src = which == 0 ? s0 : which == 1 ? s1 : which == 2 ? s2 : s3;
  u16* dst = which == 0 ? d0 : which == 1 ? d1 : which == 2 ? d2 : d3;
  const float sc = which == 0 ? scales.x : which == 1 ? scales.y : which == 2 ? scales.z : scales.w;
  int i = blockIdx.x * blockDim.x + threadIdx.x;
  const int stride = gridDim.x * blockDim.x;
  for (; i < n8; i += stride) {
    const float4* s = (const float4*)(src + (size_t)i * 8);
    float4 a = s[0];
    float4 b = s[1];
    u16x8 o;
    o[0] = f32_to_bf16(a.x * sc); o[1] = f32_to_bf16(a.y * sc);
    o[2] = f32_to_bf16(a.z * sc); o[3] = f32_to_bf16(a.w * sc);
    o[4] = f32_to_bf16(b.x * sc); o[5] = f32_to_bf16(b.y * sc);
    o[6] = f32_to_bf16(b.z * sc); o[7] = f32_to_bf16(b.w * sc);
    *(u16x8*)(dst + (size_t)i * 8) = o;
  }
}

// ---------------- GEMM core: C = (A @ W^T + bias) * oscale  (BM=128,BN=64,BK=32)
template <int MODE>
__device__ __forceinline__ void gemm_body(
    const u16* __restrict__ A, const u16* __restrict__ Bw, const float* __restrict__ bias,
    float* __restrict__ outF, u16* __restrict__ outP, float oscale,
    u16* As, u16* Bs)
{
  const int K = DM, N = DM;
  const int tid = threadIdx.x;
  const int wave = tid >> 6, lane = tid & 63;
  const int l15 = lane & 15, l4 = lane >> 4;
  const int wr = wave >> 1, wc = wave & 1;
  const int rowBase = blockIdx.y * 128, colBase = blockIdx.x * 64;

  f32x4 acc[4][2];
#pragma unroll
  for (int m = 0; m < 4; ++m)
#pragma unroll
    for (int n = 0; n < 2; ++n) acc[m][n] = (f32x4){0.f, 0.f, 0.f, 0.f};

  for (int k0 = 0; k0 < K; k0 += 32) {
#pragma unroll
    for (int c = 0; c < 2; ++c) {
      const int ldsbyte = wave * 2048 + c * 1024;
      const int elt = (ldsbyte >> 1) + lane * 8;
      const int r = elt >> 5, cc = elt & 31;
      gload_lds16(A + (size_t)(rowBase + r) * K + k0 + cc, (char*)As + ldsbyte);
    }
    {
      const int ldsbyte = wave * 1024;
      const int elt = (ldsbyte >> 1) + lane * 8;
      const int r = elt >> 5, cc = elt & 31;
      gload_lds16(Bw + (size_t)(colBase + r) * K + k0 + cc, (char*)Bs + ldsbyte);
    }
    __syncthreads();

    bf16x8 af[4], bfr[2];
#pragma unroll
    for (int m = 0; m < 4; ++m)
      af[m] = *(const bf16x8*)&As[(wr * 64 + m * 16 + l15) * 32 + 8 * l4];
#pragma unroll
    for (int n = 0; n < 2; ++n)
      bfr[n] = *(const bf16x8*)&Bs[(wc * 32 + n * 16 + l15) * 32 + 8 * l4];
#pragma unroll
    for (int m = 0; m < 4; ++m)
#pragma unroll
      for (int n = 0; n < 2; ++n)
        acc[m][n] = __builtin_amdgcn_mfma_f32_16x16x32_bf16(af[m], bfr[n], acc[m][n], 0, 0, 0);
    __syncthreads();
  }

#pragma unroll
  for (int m = 0; m < 4; ++m)
#pragma unroll
    for (int n = 0; n < 2; ++n)
#pragma unroll
      for (int j = 0; j < 4; ++j) {
        const int row = rowBase + wr * 64 + m * 16 + 4 * l4 + j;
        const int col = colBase + wc * 32 + n * 16 + l15;
        const float vv = (acc[m][n][j] + bias[col]) * oscale;
        if (MODE == 0) {
          const int s = row >> 1, b = row & 1, h = col >> 6, dh = col & 63;
          outP[((size_t)(h * BATCH + b) * S_LEN + s) * HDIM + dh] = f32_to_bf16(vv);
        } else {
          outF[(size_t)row * N + col] = vv;
        }
      }
}

// Fused QKV projection: blockIdx.z selects (A, W, bias, out, scale).
__global__ __launch_bounds__(256) void gemm_qkv(
    const u16* __restrict__ Aq, const u16* __restrict__ Ak, const u16* __restrict__ Av,
    const u16* __restrict__ Wq, const u16* __restrict__ Wk, const u16* __restrict__ Wv,
    const float* __restrict__ bq, const float* __restrict__ bk, const float* __restrict__ bv,
    u16* __restrict__ Oq, u16* __restrict__ Ok, u16* __restrict__ Ov, float qscale)
{
  __shared__ u16 As[128 * 32];
  __shared__ u16 Bs[64 * 32];
  const int z = blockIdx.z;
  const u16* A  = z == 0 ? Aq : z == 1 ? Ak : Av;
  const u16* W  = z == 0 ? Wq : z == 1 ? Wk : Wv;
  const float* b = z == 0 ? bq : z == 1 ? bk : bv;
  u16* O = z == 0 ? Oq : z == 1 ? Ok : Ov;
  const float sc = z == 0 ? qscale : 1.f;
  gemm_body<0>(A, W, b, nullptr, O, sc, As, Bs);
}

__global__ __launch_bounds__(256) void gemm_out(
    const u16* __restrict__ A, const u16* __restrict__ W, const float* __restrict__ bias,
    float* __restrict__ outF)
{
  __shared__ u16 As[128 * 32];
  __shared__ u16 Bs[64 * 32];
  gemm_body<1>(A, W, bias, outF, nullptr, 1.f, As, Bs);
}

// ---------------- flash attention v14 = round-11 minus max-tracking -----------
// Scores are bounded (unit-variance projections, /8 scale, log2 domain: |p|≲8;
// f32 exp2 overflows only past 127), so softmax runs UNNORMALIZED: pe=exp2(p)
// directly -- no running max, no fmax tree, no cross-lane max shuffles, no
// rescale branch. Partials stay normalized by l; combine uses m=0.
// K LDS [64key][64dh], XOR-swizzled 16B columns via pre-swizzled global source.
// V LDS [dh/16][key/4][key%4][dh%16] for tr_read. bf16 mask (pre-scaled log2e).
__device__ __forceinline__ void stageK_swz(const u16* __restrict__ Kp, int kt, u16* dst, int tid) {
#pragma unroll
  for (int h = 0; h < 2; ++h) {
    const int c = tid + 256 * h;              // 16B chunk id
    const int r = c >> 3, x = c & 7;
    gload_lds16(Kp + (size_t)(kt + r) * HDIM + (x ^ (r & 7)) * 8, (char*)dst + 16 * c);
  }
}
__device__ __forceinline__ void stageV(const u16* __restrict__ Vp, int kt, u16* dst, int tid) {
#pragma unroll
  for (int h = 0; h < 2; ++h) {
    const int c = tid + 256 * h;
    const int key = 4 * ((c >> 3) & 15) + ((c >> 1) & 3);
    const int dh  = 16 * (c >> 7) + 8 * (c & 1);
    gload_lds16(Vp + (size_t)(kt + key) * HDIM + dh, (char*)dst + 16 * c);
  }
}

// (256,4): 128-reg total budget -> 16 waves/CU (rounds 9/11: VGPR 64, Occ 37%).
__global__ __launch_bounds__(256, 4) void flash_attn(
    const u16* __restrict__ Qh, const u16* __restrict__ Kh, const u16* __restrict__ Vh,
    const u16* __restrict__ maskb, u16* __restrict__ Opart, float2* __restrict__ mlp)
{
  const int hb = blockIdx.y;
  const int z  = blockIdx.z;
  const int qb = blockIdx.x * 128;
  const int kbase = z * SPAN;
  const u16* Qp = Qh + (size_t)hb * S_LEN * HDIM;
  const u16* Kp = Kh + (size_t)hb * S_LEN * HDIM + (size_t)kbase * HDIM;
  const u16* Vp = Vh + (size_t)hb * S_LEN * HDIM + (size_t)kbase * HDIM;
  const u16* mp = maskb + kbase;
  const int tid = threadIdx.x;
  const int wave = tid >> 6, lane = tid & 63;
  const int l15 = lane & 15, l4 = lane >> 4;
  const int qrow0 = qb + wave * 32 + l15;    // frag 0
  const int qrow1 = qrow0 + 16;              // frag 1

  __shared__ u16 Klds[2][4096];
  __shared__ u16 Vlds[2][4096];

  bf16x8 bq[2][2];
  bq[0][0] = *(const bf16x8*)&Qp[(size_t)qrow0 * HDIM + 8 * l4];
  bq[0][1] = *(const bf16x8*)&Qp[(size_t)qrow0 * HDIM + 32 + 8 * l4];
  bq[1][0] = *(const bf16x8*)&Qp[(size_t)qrow1 * HDIM + 8 * l4];
  bq[1][1] = *(const bf16x8*)&Qp[(size_t)qrow1 * HDIM + 32 + 8 * l4];

  stageK_swz(Kp, 0, &Klds[0][0], tid);
  stageV(Vp, 0, &Vlds[0][0], tid);

  float l_run[2] = {0.f, 0.f};
  f32x4 oacc[2][4];
#pragma unroll
  for (int f = 0; f < 2; ++f)
#pragma unroll
    for (int D = 0; D < 4; ++D) oacc[f][D] = (f32x4){0.f, 0.f, 0.f, 0.f};

  __syncthreads();   // stage(0) complete (drains vmcnt)

  for (int kt = 0; kt < SPAN; kt += 64) {
    const int cur = (kt >> 6) & 1;
    if (kt + 64 < SPAN) {
      stageK_swz(Kp, kt + 64, &Klds[cur ^ 1][0], tid);
      stageV(Vp, kt + 64, &Vlds[cur ^ 1][0], tid);
    }
    // mask(t) bf16 (L2/L3-resident), consumed in softmax below
    u16x4 mc[2][4];
#pragma unroll
    for (int kb = 0; kb < 4; ++kb) {
      mc[0][kb] = *(const u16x4*)&mp[(size_t)qrow0 * S_LEN + kt + 16 * kb + 4 * l4];
      mc[1][kb] = *(const u16x4*)&mp[(size_t)qrow1 * S_LEN + kt + 16 * kb + 4 * l4];
    }

    bf16x4 pb[2][4];
#pragma unroll
    for (int f = 0; f < 2; ++f) {
      f32x4 st[4];
#pragma unroll
      for (int kb = 0; kb < 4; ++kb) {
        const int r = 16 * kb + l15;
        const int s0 = (l4 ^ (l15 & 7)) * 8;
        const int s1 = ((l4 + 4) ^ (l15 & 7)) * 8;
        bf16x8 k0 = *(const bf16x8*)&Klds[cur][r * 64 + s0];
        bf16x8 k1 = *(const bf16x8*)&Klds[cur][r * 64 + s1];
        f32x4 zz = (f32x4){0.f, 0.f, 0.f, 0.f};
        zz = __builtin_amdgcn_mfma_f32_16x16x32_bf16(k0, bq[f][0], zz, 0, 0, 0);
        zz = __builtin_amdgcn_mfma_f32_16x16x32_bf16(k1, bq[f][1], zz, 0, 0, 0);
        st[kb] = zz;
      }

      // unnormalized softmax: pe = exp2(score + mask), no max subtraction
      float rs = 0.f;
#pragma unroll
      for (int kb = 0; kb < 4; ++kb)
#pragma unroll
        for (int j = 0; j < 4; ++j) {
          const float pe = exp2f(st[kb][j] + bf2f((u16)mc[f][kb][j]));
          rs += pe;
          pb[f][kb][j] = (short)cvt_bf16(pe);
        }
      rs += __shfl_xor(rs, 16);
      rs += __shfl_xor(rs, 32);
      l_run[f] += rs;
    }

    // PV: 2 groups of {8 tr_read, lgkm(0), 16 MFMA}
    const char* vb = (const char*)&Vlds[cur][0] + 8 * lane;
#pragma unroll
    for (int g = 0; g < 2; ++g) {
      bf16x4 va[2][4];
#pragma unroll
      for (int D = 0; D < 2; ++D)
#pragma unroll
        for (int kb = 0; kb < 4; ++kb)
          va[D][kb] = tr_read(vb + 2048 * (2 * g + D) + 512 * kb);
      asm volatile("s_waitcnt lgkmcnt(0)" ::: "memory");
      __builtin_amdgcn_sched_barrier(0);
#pragma unroll
      for (int D = 0; D < 2; ++D)
#pragma unroll
        for (int kb = 0; kb < 4; ++kb) {
          oacc[0][2 * g + D] = MFMA16(va[D][kb], pb[0][kb], oacc[0][2 * g + D]);
          oacc[1][2 * g + D] = MFMA16(va[D][kb], pb[1][kb], oacc[1][2 * g + D]);
        }
    }

    __syncthreads();  // stage(t+1) DMA complete + all waves done with buf[cur]
  }

  // epilogue: normalized partial O (bf16) + (m=0, l) per row (f32)
  u16* Oz = Opart + (size_t)z * NROWS * HDIM;
#pragma unroll
  for (int f = 0; f < 2; ++f) {
    const float inv = 1.0f / l_run[f];
    const int qr = f == 0 ? qrow0 : qrow1;
    const size_t row = (size_t)hb * S_LEN + qr;
#pragma unroll
    for (int D = 0; D < 4; ++D) {
      u16x4 ov;
#pragma unroll
      for (int j = 0; j < 4; ++j) ov[j] = f32_to_bf16(oacc[f][D][j] * inv);
      *(u16x4*)&Oz[row * HDIM + 16 * D + 4 * l4] = ov;
    }
    if (l4 == 0) mlp[(size_t)z * NROWS + row] = make_float2(0.f, l_run[f]);
  }
}

// ---------------- split-K combine: Ob = merge of KSPLIT normalized partials ---
__global__ __launch_bounds__(256) void fa_combine(
    const u16* __restrict__ Opart, const float2* __restrict__ mlp, u16* __restrict__ Ob)
{
  const int idx = blockIdx.x * blockDim.x + threadIdx.x;  // NROWS*16 threads
  const int row = idx >> 4, c = idx & 15;
  float2 ml[KSPLIT];
  float m = -1e30f;
#pragma unroll
  for (int zz = 0; zz < KSPLIT; ++zz) {
    ml[zz] = mlp[(size_t)zz * NROWS + row];
    m = fmaxf(m, ml[zz].x);
  }
  float w[KSPLIT], tot = 0.f;
#pragma unroll
  for (int zz = 0; zz < KSPLIT; ++zz) {
    w[zz] = exp2f(ml[zz].x - m) * ml[zz].y;
    tot += w[zz];
  }
  const float inv = 1.f / tot;
  const size_t off = (size_t)row * HDIM + 4 * c;
  float a0 = 0.f, a1 = 0.f, a2 = 0.f, a3 = 0.f;
#pragma unroll
  for (int zz = 0; zz < KSPLIT; ++zz) {
    const u16x4 o = *(const u16x4*)&Opart[(size_t)zz * NROWS * HDIM + off];
    const float wz = w[zz] * inv;
    a0 += wz * bf2f((u16)o[0]);
    a1 += wz * bf2f((u16)o[1]);
    a2 += wz * bf2f((u16)o[2]);
    a3 += wz * bf2f((u16)o[3]);
  }
  u16x4 o;
  o[0] = f32_to_bf16(a0); o[1] = f32_to_bf16(a1);
  o[2] = f32_to_bf16(a2); o[3] = f32_to_bf16(a3);
  *(u16x4*)&Ob[off] = o;
}

// ---------------- launch ----------------
extern "C" void kernel_launch(void* const* d_in, const int* in_sizes, int n_in,
                              void* d_out, int out_size, void* d_ws, size_t ws_size,
                              hipStream_t stream) {
  const float* q    = (const float*)d_in[0];
  const float* k    = (const float*)d_in[1];
  const float* v    = (const float*)d_in[2];
  const float* mask = (const float*)d_in[3];
  const float* Wq   = (const float*)d_in[4];
  const float* bq   = (const float*)d_in[5];
  const float* Wk   = (const float*)d_in[6];
  const float* bk   = (const float*)d_in[7];
  const float* Wv   = (const float*)d_in[8];
  const float* bv   = (const float*)d_in[9];
  const float* Wo   = (const float*)d_in[10];
  const float* bo   = (const float*)d_in[11];
  float* out = (float*)d_out;

  char* ws = (char*)d_ws;
  const size_t MB = 1024 * 1024;
  // persistent region (0..42MB):
  u16*  Qh    = (u16*)(ws + 0 * MB);        // 8 MB
  u16*  Kh    = (u16*)(ws + 8 * MB);        // 8 MB
  u16*  Vh    = (u16*)(ws + 16 * MB);       // 8 MB
  u16*  maskb = (u16*)(ws + 24 * MB);       // 8 MB (S*S bf16, pre-scaled log2e)
  u16*  wob   = (u16*)(ws + 32 * MB);       // 2 MB (needed by final GEMM)
  u16*  Ob    = (u16*)(ws + 34 * MB);       // 8 MB
  // scratch region (42..72MB), phase 1: cast outputs (dead after QKV GEMM)
  u16*  qb_   = (u16*)(ws + 42 * MB);       // 8 MB
  u16*  kb_   = (u16*)(ws + 50 * MB);       // 8 MB
  u16*  vb_   = (u16*)(ws + 58 * MB);       // 8 MB
  u16*  wqb   = (u16*)(ws + 66 * MB);       // 2 MB
  u16*  wkb   = (u16*)(ws + 68 * MB);       // 2 MB
  u16*  wvb   = (u16*)(ws + 70 * MB);       // 2 MB
  // scratch region phase 2 (aliases phase 1; valid once QKV GEMM completed):
  u16*  Opart = (u16*)(ws + 42 * MB);       // 16 MB (KSPLIT=2 bf16 partials)
  float2* mlp = (float2*)(ws + 58 * MB);    // 1 MB (aliases vb_, dead by then)
  // high-water 72 MB

  const int n8_t = MROWS * DM / 8;   // 524288 (== S*S/8 for the mask)
  const int n8_w = DM * DM / 8;      // 131072
  cast4_f32_bf16<<<dim3(1024, 4), 256, 0, stream>>>(
      q, qb_, k, kb_, v, vb_, mask, maskb,
      make_float4(1.f, 1.f, 1.f, LOG2E), n8_t);
  cast4_f32_bf16<<<dim3(256, 4), 256, 0, stream>>>(
      Wq, wqb, Wk, wkb, Wv, wvb, Wo, wob,
      make_float4(1.f, 1.f, 1.f, 1.f), n8_w);

  const float qscale = 0.125f * LOG2E;     // fold 1/sqrt(hd) and log2e into Q
  gemm_qkv<<<dim3(DM / 64, MROWS / 128, 3), 256, 0, stream>>>(
      qb_, kb_, vb_, wqb, wkb, wvb, bq, bk, bv, Qh, Kh, Vh, qscale);

  flash_attn<<<dim3(S_LEN / 128, NHEAD * BATCH, KSPLIT), 256, 0, stream>>>(
      Qh, Kh, Vh, maskb, Opart, mlp);
  fa_combine<<<NROWS * 16 / 256, 256, 0, stream>>>(Opart, mlp, Ob);

  gemm_out<<<dim3(DM / 64, MROWS / 128), 256, 0, stream>>>(Ob, wob, bo, out);
}

// Round 15
// 183.098 us; speedup vs baseline: 1.0788x; 1.0788x over previous
//
#include <hip/hip_runtime.h>
#include <hip/hip_bf16.h>
#include <cstdint>
#include <cstddef>

typedef unsigned short u16;
typedef short bf16x8 __attribute__((ext_vector_type(8)));
typedef short bf16x4 __attribute__((ext_vector_type(4)));
typedef unsigned short u16x8 __attribute__((ext_vector_type(8)));
typedef unsigned short u16x4 __attribute__((ext_vector_type(4)));
typedef float f32x4 __attribute__((ext_vector_type(4)));

#define S_LEN 2048
#define BATCH 2
#define DM 1024
#define NHEAD 16
#define HDIM 64
#define MROWS (S_LEN * BATCH)  // 4096
#define LOG2E 1.44269504088896340736f
#define KSPLIT 2
#define SPAN (S_LEN / KSPLIT)  // 1024 keys per split-block
#define NROWS (NHEAD * BATCH * S_LEN)  // 65536 (hb, q) rows

__device__ __forceinline__ u16 f32_to_bf16(float f) {
  union { float f; uint32_t u; } v; v.f = f;
  uint32_t u = v.u;
  u += 0x7FFFu + ((u >> 16) & 1u);  // RNE
  return (u16)(u >> 16);
}
__device__ __forceinline__ u16 cvt_bf16(float f) {
  __hip_bfloat16 h = __float2bfloat16(f);
  return *reinterpret_cast<u16*>(&h);
}
__device__ __forceinline__ float bf2f(u16 x) {
  union { float f; uint32_t u; } v; v.u = ((uint32_t)x) << 16; return v.f;
}

__device__ __forceinline__ void gload_lds16(const void* g, void* l) {
  __builtin_amdgcn_global_load_lds(
      (const __attribute__((address_space(1))) void*)g,
      (__attribute__((address_space(3))) void*)l, 16, 0, 0);
}

// hardware transpose read: 4 bf16 per lane
__device__ __forceinline__ bf16x4 tr_read(const void* lp) {
  bf16x4 d;
  auto p = (const __attribute__((address_space(3))) short*)lp;
  asm volatile("ds_read_b64_tr_b16 %0, %1" : "=v"(d) : "v"(p));
  return d;
}

#if __has_builtin(__builtin_amdgcn_mfma_f32_16x16x16_bf16)
#define MFMA16(a, b, c) __builtin_amdgcn_mfma_f32_16x16x16_bf16(a, b, c, 0, 0, 0)
#elif __has_builtin(__builtin_amdgcn_mfma_f32_16x16x16bf16_1k)
#define MFMA16(a, b, c) __builtin_amdgcn_mfma_f32_16x16x16bf16_1k(a, b, c, 0, 0, 0)
#else
__device__ __forceinline__ f32x4 mfma16_asm(bf16x4 a, bf16x4 b, f32x4 c) {
  f32x4 d;
  asm volatile("v_mfma_f32_16x16x16_bf16 %0, %1, %2, %3\n\ts_nop 7\n\ts_nop 7"
               : "=&v"(d) : "v"(a), "v"(b), "v"(c));
  return d;
}
#define MFMA16(a, b, c) mfma16_asm(a, b, c)
#endif

// ---------------- fused fp32 -> bf16 casts: ALL 8 tensors in one launch -------
struct CastArgs {
  const float* s[8];
  u16* d[8];
};

__global__ void cast_all_f32_bf16(CastArgs a, int n8_big, int n8_small) {
  const int which = blockIdx.y;
  const float* src = a.s[which];
  u16* dst = a.d[which];
  const float sc = (which == 3) ? LOG2E : 1.f;   // slot 3 = mask (log2e-scaled)
  const int n8 = (which < 4) ? n8_big : n8_small;
  int i = blockIdx.x * blockDim.x + threadIdx.x;
  const int stride = gridDim.x * blockDim.x;
  for (; i < n8; i += stride) {
    const float4* s = (const float4*)(src + (size_t)i * 8);
    float4 x = s[0];
    float4 y = s[1];
    u16x8 o;
    o[0] = f32_to_bf16(x.x * sc); o[1] = f32_to_bf16(x.y * sc);
    o[2] = f32_to_bf16(x.z * sc); o[3] = f32_to_bf16(x.w * sc);
    o[4] = f32_to_bf16(y.x * sc); o[5] = f32_to_bf16(y.y * sc);
    o[6] = f32_to_bf16(y.z * sc); o[7] = f32_to_bf16(y.w * sc);
    *(u16x8*)(dst + (size_t)i * 8) = o;
  }
}

// ---------------- GEMM core: C = (A @ W^T + bias) * oscale  (BM=128,BN=64,BK=32)
template <int MODE>
__device__ __forceinline__ void gemm_body(
    const u16* __restrict__ A, const u16* __restrict__ Bw, const float* __restrict__ bias,
    float* __restrict__ outF, u16* __restrict__ outP, float oscale,
    u16* As, u16* Bs)
{
  const int K = DM, N = DM;
  const int tid = threadIdx.x;
  const int wave = tid >> 6, lane = tid & 63;
  const int l15 = lane & 15, l4 = lane >> 4;
  const int wr = wave >> 1, wc = wave & 1;
  const int rowBase = blockIdx.y * 128, colBase = blockIdx.x * 64;

  f32x4 acc[4][2];
#pragma unroll
  for (int m = 0; m < 4; ++m)
#pragma unroll
    for (int n = 0; n < 2; ++n) acc[m][n] = (f32x4){0.f, 0.f, 0.f, 0.f};

  for (int k0 = 0; k0 < K; k0 += 32) {
#pragma unroll
    for (int c = 0; c < 2; ++c) {
      const int ldsbyte = wave * 2048 + c * 1024;
      const int elt = (ldsbyte >> 1) + lane * 8;
      const int r = elt >> 5, cc = elt & 31;
      gload_lds16(A + (size_t)(rowBase + r) * K + k0 + cc, (char*)As + ldsbyte);
    }
    {
      const int ldsbyte = wave * 1024;
      const int elt = (ldsbyte >> 1) + lane * 8;
      const int r = elt >> 5, cc = elt & 31;
      gload_lds16(Bw + (size_t)(colBase + r) * K + k0 + cc, (char*)Bs + ldsbyte);
    }
    __syncthreads();

    bf16x8 af[4], bfr[2];
#pragma unroll
    for (int m = 0; m < 4; ++m)
      af[m] = *(const bf16x8*)&As[(wr * 64 + m * 16 + l15) * 32 + 8 * l4];
#pragma unroll
    for (int n = 0; n < 2; ++n)
      bfr[n] = *(const bf16x8*)&Bs[(wc * 32 + n * 16 + l15) * 32 + 8 * l4];
#pragma unroll
    for (int m = 0; m < 4; ++m)
#pragma unroll
      for (int n = 0; n < 2; ++n)
        acc[m][n] = __builtin_amdgcn_mfma_f32_16x16x32_bf16(af[m], bfr[n], acc[m][n], 0, 0, 0);
    __syncthreads();
  }

#pragma unroll
  for (int m = 0; m < 4; ++m)
#pragma unroll
    for (int n = 0; n < 2; ++n)
#pragma unroll
      for (int j = 0; j < 4; ++j) {
        const int row = rowBase + wr * 64 + m * 16 + 4 * l4 + j;
        const int col = colBase + wc * 32 + n * 16 + l15;
        const float vv = (acc[m][n][j] + bias[col]) * oscale;
        if (MODE == 0) {
          const int s = row >> 1, b = row & 1, h = col >> 6, dh = col & 63;
          outP[((size_t)(h * BATCH + b) * S_LEN + s) * HDIM + dh] = f32_to_bf16(vv);
        } else {
          outF[(size_t)row * N + col] = vv;
        }
      }
}

// Fused QKV projection: blockIdx.z selects (A, W, bias, out, scale).
__global__ __launch_bounds__(256) void gemm_qkv(
    const u16* __restrict__ Aq, const u16* __restrict__ Ak, const u16* __restrict__ Av,
    const u16* __restrict__ Wq, const u16* __restrict__ Wk, const u16* __restrict__ Wv,
    const float* __restrict__ bq, const float* __restrict__ bk, const float* __restrict__ bv,
    u16* __restrict__ Oq, u16* __restrict__ Ok, u16* __restrict__ Ov, float qscale)
{
  __shared__ u16 As[128 * 32];
  __shared__ u16 Bs[64 * 32];
  const int z = blockIdx.z;
  const u16* A  = z == 0 ? Aq : z == 1 ? Ak : Av;
  const u16* W  = z == 0 ? Wq : z == 1 ? Wk : Wv;
  const float* b = z == 0 ? bq : z == 1 ? bk : bv;
  u16* O = z == 0 ? Oq : z == 1 ? Ok : Ov;
  const float sc = z == 0 ? qscale : 1.f;
  gemm_body<0>(A, W, b, nullptr, O, sc, As, Bs);
}

__global__ __launch_bounds__(256) void gemm_out(
    const u16* __restrict__ A, const u16* __restrict__ W, const float* __restrict__ bias,
    float* __restrict__ outF)
{
  __shared__ u16 As[128 * 32];
  __shared__ u16 Bs[64 * 32];
  gemm_body<1>(A, W, bias, outF, nullptr, 1.f, As, Bs);
}

// ---------------- flash attention (round-11 config, the proven best) ----------
// K LDS [64key][64dh], XOR-swizzled 16B columns via pre-swizzled global source.
// V LDS [dh/16][key/4][key%4][dh%16] for tr_read. bf16 mask (pre-scaled log2e).
// NOTE: this inner loop is a sharp schedule-local optimum — 4 probed
// perturbations (kb-outer+mask-C-init, l-via-MFMA, no-max softmax, fp32 mask)
// all regressed 5-12%. Do not reorder its instruction mix.
__device__ __forceinline__ void stageK_swz(const u16* __restrict__ Kp, int kt, u16* dst, int tid) {
#pragma unroll
  for (int h = 0; h < 2; ++h) {
    const int c = tid + 256 * h;              // 16B chunk id
    const int r = c >> 3, x = c & 7;
    gload_lds16(Kp + (size_t)(kt + r) * HDIM + (x ^ (r & 7)) * 8, (char*)dst + 16 * c);
  }
}
__device__ __forceinline__ void stageV(const u16* __restrict__ Vp, int kt, u16* dst, int tid) {
#pragma unroll
  for (int h = 0; h < 2; ++h) {
    const int c = tid + 256 * h;
    const int key = 4 * ((c >> 3) & 15) + ((c >> 1) & 3);
    const int dh  = 16 * (c >> 7) + 8 * (c & 1);
    gload_lds16(Vp + (size_t)(kt + key) * HDIM + dh, (char*)dst + 16 * c);
  }
}

// (256,4): 128-reg total budget -> 16 waves/CU (rounds 9/11: VGPR 64, Occ 37%).
__global__ __launch_bounds__(256, 4) void flash_attn(
    const u16* __restrict__ Qh, const u16* __restrict__ Kh, const u16* __restrict__ Vh,
    const u16* __restrict__ maskb, u16* __restrict__ Opart, float2* __restrict__ mlp)
{
  const int hb = blockIdx.y;
  const int z  = blockIdx.z;
  const int qb = blockIdx.x * 128;
  const int kbase = z * SPAN;
  const u16* Qp = Qh + (size_t)hb * S_LEN * HDIM;
  const u16* Kp = Kh + (size_t)hb * S_LEN * HDIM + (size_t)kbase * HDIM;
  const u16* Vp = Vh + (size_t)hb * S_LEN * HDIM + (size_t)kbase * HDIM;
  const u16* mp = maskb + kbase;
  const int tid = threadIdx.x;
  const int wave = tid >> 6, lane = tid & 63;
  const int l15 = lane & 15, l4 = lane >> 4;
  const int qrow0 = qb + wave * 32 + l15;    // frag 0
  const int qrow1 = qrow0 + 16;              // frag 1

  __shared__ u16 Klds[2][4096];
  __shared__ u16 Vlds[2][4096];

  bf16x8 bq[2][2];
  bq[0][0] = *(const bf16x8*)&Qp[(size_t)qrow0 * HDIM + 8 * l4];
  bq[0][1] = *(const bf16x8*)&Qp[(size_t)qrow0 * HDIM + 32 + 8 * l4];
  bq[1][0] = *(const bf16x8*)&Qp[(size_t)qrow1 * HDIM + 8 * l4];
  bq[1][1] = *(const bf16x8*)&Qp[(size_t)qrow1 * HDIM + 32 + 8 * l4];

  stageK_swz(Kp, 0, &Klds[0][0], tid);
  stageV(Vp, 0, &Vlds[0][0], tid);

  float m_run[2] = {-1e30f, -1e30f}, l_run[2] = {0.f, 0.f};
  f32x4 oacc[2][4];
#pragma unroll
  for (int f = 0; f < 2; ++f)
#pragma unroll
    for (int D = 0; D < 4; ++D) oacc[f][D] = (f32x4){0.f, 0.f, 0.f, 0.f};

  __syncthreads();   // stage(0) complete (drains vmcnt)

  for (int kt = 0; kt < SPAN; kt += 64) {
    const int cur = (kt >> 6) & 1;
    if (kt + 64 < SPAN) {
      stageK_swz(Kp, kt + 64, &Klds[cur ^ 1][0], tid);
      stageV(Vp, kt + 64, &Vlds[cur ^ 1][0], tid);
    }
    // mask(t) bf16 (L2/L3-resident), consumed in softmax below
    u16x4 mc[2][4];
#pragma unroll
    for (int kb = 0; kb < 4; ++kb) {
      mc[0][kb] = *(const u16x4*)&mp[(size_t)qrow0 * S_LEN + kt + 16 * kb + 4 * l4];
      mc[1][kb] = *(const u16x4*)&mp[(size_t)qrow1 * S_LEN + kt + 16 * kb + 4 * l4];
    }

    bf16x4 pb[2][4];
#pragma unroll
    for (int f = 0; f < 2; ++f) {
      f32x4 st[4];
#pragma unroll
      for (int kb = 0; kb < 4; ++kb) {
        const int r = 16 * kb + l15;
        const int s0 = (l4 ^ (l15 & 7)) * 8;
        const int s1 = ((l4 + 4) ^ (l15 & 7)) * 8;
        bf16x8 k0 = *(const bf16x8*)&Klds[cur][r * 64 + s0];
        bf16x8 k1 = *(const bf16x8*)&Klds[cur][r * 64 + s1];
        f32x4 zz = (f32x4){0.f, 0.f, 0.f, 0.f};
        zz = __builtin_amdgcn_mfma_f32_16x16x32_bf16(k0, bq[f][0], zz, 0, 0, 0);
        zz = __builtin_amdgcn_mfma_f32_16x16x32_bf16(k1, bq[f][1], zz, 0, 0, 0);
        st[kb] = zz;
      }
      float p[16];
#pragma unroll
      for (int kb = 0; kb < 4; ++kb)
#pragma unroll
        for (int j = 0; j < 4; ++j)
          p[4 * kb + j] = st[kb][j] + bf2f((u16)mc[f][kb][j]);

      float t0 = fmaxf(fmaxf(p[0], p[1]), fmaxf(p[2], p[3]));
      float t1 = fmaxf(fmaxf(p[4], p[5]), fmaxf(p[6], p[7]));
      float t2 = fmaxf(fmaxf(p[8], p[9]), fmaxf(p[10], p[11]));
      float t3 = fmaxf(fmaxf(p[12], p[13]), fmaxf(p[14], p[15]));
      float tm = fmaxf(fmaxf(t0, t1), fmaxf(t2, t3));
      tm = fmaxf(tm, __shfl_xor(tm, 16));
      tm = fmaxf(tm, __shfl_xor(tm, 32));

      if (!__all(tm - m_run[f] <= 11.0f)) {   // defer-max (T13)
        const float mn_ = fmaxf(m_run[f], tm);
        const float fac = exp2f(m_run[f] - mn_);
#pragma unroll
        for (int D = 0; D < 4; ++D)
#pragma unroll
          for (int j = 0; j < 4; ++j) oacc[f][D][j] *= fac;
        l_run[f] *= fac;
        m_run[f] = mn_;
      }

      float rs = 0.f;
#pragma unroll
      for (int kb = 0; kb < 4; ++kb)
#pragma unroll
        for (int e = 0; e < 4; ++e) {
          const float pe = exp2f(p[4 * kb + e] - m_run[f]);
          rs += pe;
          pb[f][kb][e] = (short)cvt_bf16(pe);
        }
      rs += __shfl_xor(rs, 16);
      rs += __shfl_xor(rs, 32);
      l_run[f] += rs;
    }

    // PV: 2 groups of {8 tr_read, lgkm(0), 16 MFMA}
    const char* vb = (const char*)&Vlds[cur][0] + 8 * lane;
#pragma unroll
    for (int g = 0; g < 2; ++g) {
      bf16x4 va[2][4];
#pragma unroll
      for (int D = 0; D < 2; ++D)
#pragma unroll
        for (int kb = 0; kb < 4; ++kb)
          va[D][kb] = tr_read(vb + 2048 * (2 * g + D) + 512 * kb);
      asm volatile("s_waitcnt lgkmcnt(0)" ::: "memory");
      __builtin_amdgcn_sched_barrier(0);
#pragma unroll
      for (int D = 0; D < 2; ++D)
#pragma unroll
        for (int kb = 0; kb < 4; ++kb) {
          oacc[0][2 * g + D] = MFMA16(va[D][kb], pb[0][kb], oacc[0][2 * g + D]);
          oacc[1][2 * g + D] = MFMA16(va[D][kb], pb[1][kb], oacc[1][2 * g + D]);
        }
    }

    __syncthreads();  // stage(t+1) DMA complete + all waves done with buf[cur]
  }

  // epilogue: normalized partial O (bf16) + (m, l) per row (f32)
  u16* Oz = Opart + (size_t)z * NROWS * HDIM;
#pragma unroll
  for (int f = 0; f < 2; ++f) {
    const float inv = 1.0f / l_run[f];
    const int qr = f == 0 ? qrow0 : qrow1;
    const size_t row = (size_t)hb * S_LEN + qr;
#pragma unroll
    for (int D = 0; D < 4; ++D) {
      u16x4 ov;
#pragma unroll
      for (int j = 0; j < 4; ++j) ov[j] = f32_to_bf16(oacc[f][D][j] * inv);
      *(u16x4*)&Oz[row * HDIM + 16 * D + 4 * l4] = ov;
    }
    if (l4 == 0) mlp[(size_t)z * NROWS + row] = make_float2(m_run[f], l_run[f]);
  }
}

// ---------------- split-K combine: Ob = merge of KSPLIT normalized partials ---
__global__ __launch_bounds__(256) void fa_combine(
    const u16* __restrict__ Opart, const float2* __restrict__ mlp, u16* __restrict__ Ob)
{
  const int idx = blockIdx.x * blockDim.x + threadIdx.x;  // NROWS*16 threads
  const int row = idx >> 4, c = idx & 15;
  float2 ml[KSPLIT];
  float m = -1e30f;
#pragma unroll
  for (int zz = 0; zz < KSPLIT; ++zz) {
    ml[zz] = mlp[(size_t)zz * NROWS + row];
    m = fmaxf(m, ml[zz].x);
  }
  float w[KSPLIT], tot = 0.f;
#pragma unroll
  for (int zz = 0; zz < KSPLIT; ++zz) {
    w[zz] = exp2f(ml[zz].x - m) * ml[zz].y;
    tot += w[zz];
  }
  const float inv = 1.f / tot;
  const size_t off = (size_t)row * HDIM + 4 * c;
  float a0 = 0.f, a1 = 0.f, a2 = 0.f, a3 = 0.f;
#pragma unroll
  for (int zz = 0; zz < KSPLIT; ++zz) {
    const u16x4 o = *(const u16x4*)&Opart[(size_t)zz * NROWS * HDIM + off];
    const float wz = w[zz] * inv;
    a0 += wz * bf2f((u16)o[0]);
    a1 += wz * bf2f((u16)o[1]);
    a2 += wz * bf2f((u16)o[2]);
    a3 += wz * bf2f((u16)o[3]);
  }
  u16x4 o;
  o[0] = f32_to_bf16(a0); o[1] = f32_to_bf16(a1);
  o[2] = f32_to_bf16(a2); o[3] = f32_to_bf16(a3);
  *(u16x4*)&Ob[off] = o;
}

// ---------------- launch ----------------
extern "C" void kernel_launch(void* const* d_in, const int* in_sizes, int n_in,
                              void* d_out, int out_size, void* d_ws, size_t ws_size,
                              hipStream_t stream) {
  const float* q    = (const float*)d_in[0];
  const float* k    = (const float*)d_in[1];
  const float* v    = (const float*)d_in[2];
  const float* mask = (const float*)d_in[3];
  const float* Wq   = (const float*)d_in[4];
  const float* bq   = (const float*)d_in[5];
  const float* Wk   = (const float*)d_in[6];
  const float* bk   = (const float*)d_in[7];
  const float* Wv   = (const float*)d_in[8];
  const float* bv   = (const float*)d_in[9];
  const float* Wo   = (const float*)d_in[10];
  const float* bo   = (const float*)d_in[11];
  float* out = (float*)d_out;

  char* ws = (char*)d_ws;
  const size_t MB = 1024 * 1024;
  // persistent region (0..42MB):
  u16*  Qh    = (u16*)(ws + 0 * MB);        // 8 MB
  u16*  Kh    = (u16*)(ws + 8 * MB);        // 8 MB
  u16*  Vh    = (u16*)(ws + 16 * MB);       // 8 MB
  u16*  maskb = (u16*)(ws + 24 * MB);       // 8 MB (S*S bf16, pre-scaled log2e)
  u16*  wob   = (u16*)(ws + 32 * MB);       // 2 MB (needed by final GEMM)
  u16*  Ob    = (u16*)(ws + 34 * MB);       // 8 MB
  // scratch region (42..72MB), phase 1: cast outputs (dead after QKV GEMM)
  u16*  qb_   = (u16*)(ws + 42 * MB);       // 8 MB
  u16*  kb_   = (u16*)(ws + 50 * MB);       // 8 MB
  u16*  vb_   = (u16*)(ws + 58 * MB);       // 8 MB
  u16*  wqb   = (u16*)(ws + 66 * MB);       // 2 MB
  u16*  wkb   = (u16*)(ws + 68 * MB);       // 2 MB
  u16*  wvb   = (u16*)(ws + 70 * MB);       // 2 MB
  // scratch region phase 2 (aliases phase 1; valid once QKV GEMM completed):
  u16*  Opart = (u16*)(ws + 42 * MB);       // 16 MB (KSPLIT=2 bf16 partials)
  float2* mlp = (float2*)(ws + 58 * MB);    // 1 MB (aliases vb_, dead by then)
  // high-water 72 MB

  const int n8_t = MROWS * DM / 8;   // 524288 (== S*S/8 for the mask)
  const int n8_w = DM * DM / 8;      // 131072

  CastArgs ca;
  ca.s[0] = q;    ca.d[0] = qb_;
  ca.s[1] = k;    ca.d[1] = kb_;
  ca.s[2] = v;    ca.d[2] = vb_;
  ca.s[3] = mask; ca.d[3] = maskb;
  ca.s[4] = Wq;   ca.d[4] = wqb;
  ca.s[5] = Wk;   ca.d[5] = wkb;
  ca.s[6] = Wv;   ca.d[6] = wvb;
  ca.s[7] = Wo;   ca.d[7] = wob;
  cast_all_f32_bf16<<<dim3(1024, 8), 256, 0, stream>>>(ca, n8_t, n8_w);

  const float qscale = 0.125f * LOG2E;     // fold 1/sqrt(hd) and log2e into Q
  gemm_qkv<<<dim3(DM / 64, MROWS / 128, 3), 256, 0, stream>>>(
      qb_, kb_, vb_, wqb, wkb, wvb, bq, bk, bv, Qh, Kh, Vh, qscale);

  flash_attn<<<dim3(S_LEN / 128, NHEAD * BATCH, KSPLIT), 256, 0, stream>>>(
      Qh, Kh, Vh, maskb, Opart, mlp);
  fa_combine<<<NROWS * 16 / 256, 256, 0, stream>>>(Opart, mlp, Ob);

  gemm_out<<<dim3(DM / 64, MROWS / 128), 256, 0, stream>>>(Ob, wob, bo, out);
}

// Round 16
// 181.930 us; speedup vs baseline: 1.0857x; 1.0064x over previous
//
#include <hip/hip_runtime.h>
#include <hip/hip_bf16.h>
#include <cstdint>
#include <cstddef>

typedef unsigned short u16;
typedef short bf16x8 __attribute__((ext_vector_type(8)));
typedef short bf16x4 __attribute__((ext_vector_type(4)));
typedef unsigned short u16x8 __attribute__((ext_vector_type(8)));
typedef unsigned short u16x4 __attribute__((ext_vector_type(4)));
typedef float f32x4 __attribute__((ext_vector_type(4)));

#define S_LEN 2048
#define BATCH 2
#define DM 1024
#define NHEAD 16
#define HDIM 64
#define MROWS (S_LEN * BATCH)  // 4096
#define LOG2E 1.44269504088896340736f
#define KSPLIT 2
#define SPAN (S_LEN / KSPLIT)  // 1024 keys per split-block
#define NROWS (NHEAD * BATCH * S_LEN)  // 65536 (hb, q) rows

__device__ __forceinline__ u16 f32_to_bf16(float f) {
  union { float f; uint32_t u; } v; v.f = f;
  uint32_t u = v.u;
  u += 0x7FFFu + ((u >> 16) & 1u);  // RNE
  return (u16)(u >> 16);
}
__device__ __forceinline__ u16 cvt_bf16(float f) {
  __hip_bfloat16 h = __float2bfloat16(f);
  return *reinterpret_cast<u16*>(&h);
}
__device__ __forceinline__ float bf2f(u16 x) {
  union { float f; uint32_t u; } v; v.u = ((uint32_t)x) << 16; return v.f;
}

__device__ __forceinline__ void gload_lds16(const void* g, void* l) {
  __builtin_amdgcn_global_load_lds(
      (const __attribute__((address_space(1))) void*)g,
      (__attribute__((address_space(3))) void*)l, 16, 0, 0);
}

// hardware transpose read: 4 bf16 per lane
__device__ __forceinline__ bf16x4 tr_read(const void* lp) {
  bf16x4 d;
  auto p = (const __attribute__((address_space(3))) short*)lp;
  asm volatile("ds_read_b64_tr_b16 %0, %1" : "=v"(d) : "v"(p));
  return d;
}

#if __has_builtin(__builtin_amdgcn_mfma_f32_16x16x16_bf16)
#define MFMA16(a, b, c) __builtin_amdgcn_mfma_f32_16x16x16_bf16(a, b, c, 0, 0, 0)
#elif __has_builtin(__builtin_amdgcn_mfma_f32_16x16x16bf16_1k)
#define MFMA16(a, b, c) __builtin_amdgcn_mfma_f32_16x16x16bf16_1k(a, b, c, 0, 0, 0)
#else
__device__ __forceinline__ f32x4 mfma16_asm(bf16x4 a, bf16x4 b, f32x4 c) {
  f32x4 d;
  asm volatile("v_mfma_f32_16x16x16_bf16 %0, %1, %2, %3\n\ts_nop 7\n\ts_nop 7"
               : "=&v"(d) : "v"(a), "v"(b), "v"(c));
  return d;
}
#define MFMA16(a, b, c) mfma16_asm(a, b, c)
#endif

// ---------------- fused fp32 -> bf16 casts: ALL 8 tensors in one launch -------
struct CastArgs {
  const float* s[8];
  u16* d[8];
};

__global__ void cast_all_f32_bf16(CastArgs a, int n8_big, int n8_small) {
  const int which = blockIdx.y;
  const float* src = a.s[which];
  u16* dst = a.d[which];
  const float sc = (which == 3) ? LOG2E : 1.f;   // slot 3 = mask (log2e-scaled)
  const int n8 = (which < 4) ? n8_big : n8_small;
  int i = blockIdx.x * blockDim.x + threadIdx.x;
  const int stride = gridDim.x * blockDim.x;
  for (; i < n8; i += stride) {
    const float4* s = (const float4*)(src + (size_t)i * 8);
    float4 x = s[0];
    float4 y = s[1];
    u16x8 o;
    o[0] = f32_to_bf16(x.x * sc); o[1] = f32_to_bf16(x.y * sc);
    o[2] = f32_to_bf16(x.z * sc); o[3] = f32_to_bf16(x.w * sc);
    o[4] = f32_to_bf16(y.x * sc); o[5] = f32_to_bf16(y.y * sc);
    o[6] = f32_to_bf16(y.z * sc); o[7] = f32_to_bf16(y.w * sc);
    *(u16x8*)(dst + (size_t)i * 8) = o;
  }
}

// ---------------- GEMM core: C = (A @ W^T + bias) * oscale  (BM=128,BN=64,BK=32)
template <int MODE>
__device__ __forceinline__ void gemm_body(
    const u16* __restrict__ A, const u16* __restrict__ Bw, const float* __restrict__ bias,
    float* __restrict__ outF, u16* __restrict__ outP, float oscale,
    u16* As, u16* Bs)
{
  const int K = DM, N = DM;
  const int tid = threadIdx.x;
  const int wave = tid >> 6, lane = tid & 63;
  const int l15 = lane & 15, l4 = lane >> 4;
  const int wr = wave >> 1, wc = wave & 1;
  const int rowBase = blockIdx.y * 128, colBase = blockIdx.x * 64;

  f32x4 acc[4][2];
#pragma unroll
  for (int m = 0; m < 4; ++m)
#pragma unroll
    for (int n = 0; n < 2; ++n) acc[m][n] = (f32x4){0.f, 0.f, 0.f, 0.f};

  for (int k0 = 0; k0 < K; k0 += 32) {
#pragma unroll
    for (int c = 0; c < 2; ++c) {
      const int ldsbyte = wave * 2048 + c * 1024;
      const int elt = (ldsbyte >> 1) + lane * 8;
      const int r = elt >> 5, cc = elt & 31;
      gload_lds16(A + (size_t)(rowBase + r) * K + k0 + cc, (char*)As + ldsbyte);
    }
    {
      const int ldsbyte = wave * 1024;
      const int elt = (ldsbyte >> 1) + lane * 8;
      const int r = elt >> 5, cc = elt & 31;
      gload_lds16(Bw + (size_t)(colBase + r) * K + k0 + cc, (char*)Bs + ldsbyte);
    }
    __syncthreads();

    bf16x8 af[4], bfr[2];
#pragma unroll
    for (int m = 0; m < 4; ++m)
      af[m] = *(const bf16x8*)&As[(wr * 64 + m * 16 + l15) * 32 + 8 * l4];
#pragma unroll
    for (int n = 0; n < 2; ++n)
      bfr[n] = *(const bf16x8*)&Bs[(wc * 32 + n * 16 + l15) * 32 + 8 * l4];
#pragma unroll
    for (int m = 0; m < 4; ++m)
#pragma unroll
      for (int n = 0; n < 2; ++n)
        acc[m][n] = __builtin_amdgcn_mfma_f32_16x16x32_bf16(af[m], bfr[n], acc[m][n], 0, 0, 0);
    __syncthreads();
  }

#pragma unroll
  for (int m = 0; m < 4; ++m)
#pragma unroll
    for (int n = 0; n < 2; ++n)
#pragma unroll
      for (int j = 0; j < 4; ++j) {
        const int row = rowBase + wr * 64 + m * 16 + 4 * l4 + j;
        const int col = colBase + wc * 32 + n * 16 + l15;
        const float vv = (acc[m][n][j] + bias[col]) * oscale;
        if (MODE == 0) {
          const int s = row >> 1, b = row & 1, h = col >> 6, dh = col & 63;
          outP[((size_t)(h * BATCH + b) * S_LEN + s) * HDIM + dh] = f32_to_bf16(vv);
        } else {
          outF[(size_t)row * N + col] = vv;
        }
      }
}

// Fused QKV projection: blockIdx.z selects (A, W, bias, out, scale).
__global__ __launch_bounds__(256) void gemm_qkv(
    const u16* __restrict__ Aq, const u16* __restrict__ Ak, const u16* __restrict__ Av,
    const u16* __restrict__ Wq, const u16* __restrict__ Wk, const u16* __restrict__ Wv,
    const float* __restrict__ bq, const float* __restrict__ bk, const float* __restrict__ bv,
    u16* __restrict__ Oq, u16* __restrict__ Ok, u16* __restrict__ Ov, float qscale)
{
  __shared__ u16 As[128 * 32];
  __shared__ u16 Bs[64 * 32];
  const int z = blockIdx.z;
  const u16* A  = z == 0 ? Aq : z == 1 ? Ak : Av;
  const u16* W  = z == 0 ? Wq : z == 1 ? Wk : Wv;
  const float* b = z == 0 ? bq : z == 1 ? bk : bv;
  u16* O = z == 0 ? Oq : z == 1 ? Ok : Ov;
  const float sc = z == 0 ? qscale : 1.f;
  gemm_body<0>(A, W, b, nullptr, O, sc, As, Bs);
}

__global__ __launch_bounds__(256) void gemm_out(
    const u16* __restrict__ A, const u16* __restrict__ W, const float* __restrict__ bias,
    float* __restrict__ outF)
{
  __shared__ u16 As[128 * 32];
  __shared__ u16 Bs[64 * 32];
  gemm_body<1>(A, W, bias, outF, nullptr, 1.f, As, Bs);
}

// ---------------- flash attention (round-11 inner loop + XCD-aware swizzle) ---
// K LDS [64key][64dh], XOR-swizzled 16B columns via pre-swizzled global source.
// V LDS [dh/16][key/4][key%4][dh%16] for tr_read. bf16 mask (pre-scaled log2e).
// NOTE: this inner loop is a sharp schedule-local optimum — 4 probed
// perturbations (kb-outer+mask-C-init, l-via-MFMA, no-max softmax, fp32 mask)
// all regressed 5-12%. Do not reorder its instruction mix.
// T1: 1D grid, bijective remap so each XCD owns 4 contiguous head-batches
// (K/V footprint 2MB -> fits 4MB per-XCD L2; default round-robin thrashed it).
__device__ __forceinline__ void stageK_swz(const u16* __restrict__ Kp, int kt, u16* dst, int tid) {
#pragma unroll
  for (int h = 0; h < 2; ++h) {
    const int c = tid + 256 * h;              // 16B chunk id
    const int r = c >> 3, x = c & 7;
    gload_lds16(Kp + (size_t)(kt + r) * HDIM + (x ^ (r & 7)) * 8, (char*)dst + 16 * c);
  }
}
__device__ __forceinline__ void stageV(const u16* __restrict__ Vp, int kt, u16* dst, int tid) {
#pragma unroll
  for (int h = 0; h < 2; ++h) {
    const int c = tid + 256 * h;
    const int key = 4 * ((c >> 3) & 15) + ((c >> 1) & 3);
    const int dh  = 16 * (c >> 7) + 8 * (c & 1);
    gload_lds16(Vp + (size_t)(kt + key) * HDIM + dh, (char*)dst + 16 * c);
  }
}

// (256,4): 128-reg total budget -> 16 waves/CU (rounds 9/11/15: VGPR 64).
__global__ __launch_bounds__(256, 4) void flash_attn(
    const u16* __restrict__ Qh, const u16* __restrict__ Kh, const u16* __restrict__ Vh,
    const u16* __restrict__ maskb, u16* __restrict__ Opart, float2* __restrict__ mlp)
{
  // XCD-aware bijective remap: flat in [0,1024); XCD = flat%8 (dispatch order);
  // each XCD's 128 logical ids cover 4 consecutive hb (hb-major: hb*32 + z*16 + qbi).
  const int flat = blockIdx.x;
  const int idx  = ((flat & 7) << 7) + (flat >> 3);   // bijective, nwg%8==0
  const int hb  = idx >> 5;
  const int z   = (idx >> 4) & 1;
  const int qb  = (idx & 15) * 128;
  const int kbase = z * SPAN;
  const u16* Qp = Qh + (size_t)hb * S_LEN * HDIM;
  const u16* Kp = Kh + (size_t)hb * S_LEN * HDIM + (size_t)kbase * HDIM;
  const u16* Vp = Vh + (size_t)hb * S_LEN * HDIM + (size_t)kbase * HDIM;
  const u16* mp = maskb + kbase;
  const int tid = threadIdx.x;
  const int wave = tid >> 6, lane = tid & 63;
  const int l15 = lane & 15, l4 = lane >> 4;
  const int qrow0 = qb + wave * 32 + l15;    // frag 0
  const int qrow1 = qrow0 + 16;              // frag 1

  __shared__ u16 Klds[2][4096];
  __shared__ u16 Vlds[2][4096];

  bf16x8 bq[2][2];
  bq[0][0] = *(const bf16x8*)&Qp[(size_t)qrow0 * HDIM + 8 * l4];
  bq[0][1] = *(const bf16x8*)&Qp[(size_t)qrow0 * HDIM + 32 + 8 * l4];
  bq[1][0] = *(const bf16x8*)&Qp[(size_t)qrow1 * HDIM + 8 * l4];
  bq[1][1] = *(const bf16x8*)&Qp[(size_t)qrow1 * HDIM + 32 + 8 * l4];

  stageK_swz(Kp, 0, &Klds[0][0], tid);
  stageV(Vp, 0, &Vlds[0][0], tid);

  float m_run[2] = {-1e30f, -1e30f}, l_run[2] = {0.f, 0.f};
  f32x4 oacc[2][4];
#pragma unroll
  for (int f = 0; f < 2; ++f)
#pragma unroll
    for (int D = 0; D < 4; ++D) oacc[f][D] = (f32x4){0.f, 0.f, 0.f, 0.f};

  __syncthreads();   // stage(0) complete (drains vmcnt)

  for (int kt = 0; kt < SPAN; kt += 64) {
    const int cur = (kt >> 6) & 1;
    if (kt + 64 < SPAN) {
      stageK_swz(Kp, kt + 64, &Klds[cur ^ 1][0], tid);
      stageV(Vp, kt + 64, &Vlds[cur ^ 1][0], tid);
    }
    // mask(t) bf16 (L2/L3-resident), consumed in softmax below
    u16x4 mc[2][4];
#pragma unroll
    for (int kb = 0; kb < 4; ++kb) {
      mc[0][kb] = *(const u16x4*)&mp[(size_t)qrow0 * S_LEN + kt + 16 * kb + 4 * l4];
      mc[1][kb] = *(const u16x4*)&mp[(size_t)qrow1 * S_LEN + kt + 16 * kb + 4 * l4];
    }

    bf16x4 pb[2][4];
#pragma unroll
    for (int f = 0; f < 2; ++f) {
      f32x4 st[4];
#pragma unroll
      for (int kb = 0; kb < 4; ++kb) {
        const int r = 16 * kb + l15;
        const int s0 = (l4 ^ (l15 & 7)) * 8;
        const int s1 = ((l4 + 4) ^ (l15 & 7)) * 8;
        bf16x8 k0 = *(const bf16x8*)&Klds[cur][r * 64 + s0];
        bf16x8 k1 = *(const bf16x8*)&Klds[cur][r * 64 + s1];
        f32x4 zz = (f32x4){0.f, 0.f, 0.f, 0.f};
        zz = __builtin_amdgcn_mfma_f32_16x16x32_bf16(k0, bq[f][0], zz, 0, 0, 0);
        zz = __builtin_amdgcn_mfma_f32_16x16x32_bf16(k1, bq[f][1], zz, 0, 0, 0);
        st[kb] = zz;
      }
      float p[16];
#pragma unroll
      for (int kb = 0; kb < 4; ++kb)
#pragma unroll
        for (int j = 0; j < 4; ++j)
          p[4 * kb + j] = st[kb][j] + bf2f((u16)mc[f][kb][j]);

      float t0 = fmaxf(fmaxf(p[0], p[1]), fmaxf(p[2], p[3]));
      float t1 = fmaxf(fmaxf(p[4], p[5]), fmaxf(p[6], p[7]));
      float t2 = fmaxf(fmaxf(p[8], p[9]), fmaxf(p[10], p[11]));
      float t3 = fmaxf(fmaxf(p[12], p[13]), fmaxf(p[14], p[15]));
      float tm = fmaxf(fmaxf(t0, t1), fmaxf(t2, t3));
      tm = fmaxf(tm, __shfl_xor(tm, 16));
      tm = fmaxf(tm, __shfl_xor(tm, 32));

      if (!__all(tm - m_run[f] <= 11.0f)) {   // defer-max (T13)
        const float mn_ = fmaxf(m_run[f], tm);
        const float fac = exp2f(m_run[f] - mn_);
#pragma unroll
        for (int D = 0; D < 4; ++D)
#pragma unroll
          for (int j = 0; j < 4; ++j) oacc[f][D][j] *= fac;
        l_run[f] *= fac;
        m_run[f] = mn_;
      }

      float rs = 0.f;
#pragma unroll
      for (int kb = 0; kb < 4; ++kb)
#pragma unroll
        for (int e = 0; e < 4; ++e) {
          const float pe = exp2f(p[4 * kb + e] - m_run[f]);
          rs += pe;
          pb[f][kb][e] = (short)cvt_bf16(pe);
        }
      rs += __shfl_xor(rs, 16);
      rs += __shfl_xor(rs, 32);
      l_run[f] += rs;
    }

    // PV: 2 groups of {8 tr_read, lgkm(0), 16 MFMA}
    const char* vb = (const char*)&Vlds[cur][0] + 8 * lane;
#pragma unroll
    for (int g = 0; g < 2; ++g) {
      bf16x4 va[2][4];
#pragma unroll
      for (int D = 0; D < 2; ++D)
#pragma unroll
        for (int kb = 0; kb < 4; ++kb)
          va[D][kb] = tr_read(vb + 2048 * (2 * g + D) + 512 * kb);
      asm volatile("s_waitcnt lgkmcnt(0)" ::: "memory");
      __builtin_amdgcn_sched_barrier(0);
#pragma unroll
      for (int D = 0; D < 2; ++D)
#pragma unroll
        for (int kb = 0; kb < 4; ++kb) {
          oacc[0][2 * g + D] = MFMA16(va[D][kb], pb[0][kb], oacc[0][2 * g + D]);
          oacc[1][2 * g + D] = MFMA16(va[D][kb], pb[1][kb], oacc[1][2 * g + D]);
        }
    }

    __syncthreads();  // stage(t+1) DMA complete + all waves done with buf[cur]
  }

  // epilogue: normalized partial O (bf16) + (m, l) per row (f32)
  u16* Oz = Opart + (size_t)z * NROWS * HDIM;
#pragma unroll
  for (int f = 0; f < 2; ++f) {
    const float inv = 1.0f / l_run[f];
    const int qr = f == 0 ? qrow0 : qrow1;
    const size_t row = (size_t)hb * S_LEN + qr;
#pragma unroll
    for (int D = 0; D < 4; ++D) {
      u16x4 ov;
#pragma unroll
      for (int j = 0; j < 4; ++j) ov[j] = f32_to_bf16(oacc[f][D][j] * inv);
      *(u16x4*)&Oz[row * HDIM + 16 * D + 4 * l4] = ov;
    }
    if (l4 == 0) mlp[(size_t)z * NROWS + row] = make_float2(m_run[f], l_run[f]);
  }
}

// ---------------- split-K combine: Ob = merge of KSPLIT normalized partials ---
__global__ __launch_bounds__(256) void fa_combine(
    const u16* __restrict__ Opart, const float2* __restrict__ mlp, u16* __restrict__ Ob)
{
  const int idx = blockIdx.x * blockDim.x + threadIdx.x;  // NROWS*16 threads
  const int row = idx >> 4, c = idx & 15;
  float2 ml[KSPLIT];
  float m = -1e30f;
#pragma unroll
  for (int zz = 0; zz < KSPLIT; ++zz) {
    ml[zz] = mlp[(size_t)zz * NROWS + row];
    m = fmaxf(m, ml[zz].x);
  }
  float w[KSPLIT], tot = 0.f;
#pragma unroll
  for (int zz = 0; zz < KSPLIT; ++zz) {
    w[zz] = exp2f(ml[zz].x - m) * ml[zz].y;
    tot += w[zz];
  }
  const float inv = 1.f / tot;
  const size_t off = (size_t)row * HDIM + 4 * c;
  float a0 = 0.f, a1 = 0.f, a2 = 0.f, a3 = 0.f;
#pragma unroll
  for (int zz = 0; zz < KSPLIT; ++zz) {
    const u16x4 o = *(const u16x4*)&Opart[(size_t)zz * NROWS * HDIM + off];
    const float wz = w[zz] * inv;
    a0 += wz * bf2f((u16)o[0]);
    a1 += wz * bf2f((u16)o[1]);
    a2 += wz * bf2f((u16)o[2]);
    a3 += wz * bf2f((u16)o[3]);
  }
  u16x4 o;
  o[0] = f32_to_bf16(a0); o[1] = f32_to_bf16(a1);
  o[2] = f32_to_bf16(a2); o[3] = f32_to_bf16(a3);
  *(u16x4*)&Ob[off] = o;
}

// ---------------- launch ----------------
extern "C" void kernel_launch(void* const* d_in, const int* in_sizes, int n_in,
                              void* d_out, int out_size, void* d_ws, size_t ws_size,
                              hipStream_t stream) {
  const float* q    = (const float*)d_in[0];
  const float* k    = (const float*)d_in[1];
  const float* v    = (const float*)d_in[2];
  const float* mask = (const float*)d_in[3];
  const float* Wq   = (const float*)d_in[4];
  const float* bq   = (const float*)d_in[5];
  const float* Wk   = (const float*)d_in[6];
  const float* bk   = (const float*)d_in[7];
  const float* Wv   = (const float*)d_in[8];
  const float* bv   = (const float*)d_in[9];
  const float* Wo   = (const float*)d_in[10];
  const float* bo   = (const float*)d_in[11];
  float* out = (float*)d_out;

  char* ws = (char*)d_ws;
  const size_t MB = 1024 * 1024;
  // persistent region (0..42MB):
  u16*  Qh    = (u16*)(ws + 0 * MB);        // 8 MB
  u16*  Kh    = (u16*)(ws + 8 * MB);        // 8 MB
  u16*  Vh    = (u16*)(ws + 16 * MB);       // 8 MB
  u16*  maskb = (u16*)(ws + 24 * MB);       // 8 MB (S*S bf16, pre-scaled log2e)
  u16*  wob   = (u16*)(ws + 32 * MB);       // 2 MB (needed by final GEMM)
  u16*  Ob    = (u16*)(ws + 34 * MB);       // 8 MB
  // scratch region (42..72MB), phase 1: cast outputs (dead after QKV GEMM)
  u16*  qb_   = (u16*)(ws + 42 * MB);       // 8 MB
  u16*  kb_   = (u16*)(ws + 50 * MB);       // 8 MB
  u16*  vb_   = (u16*)(ws + 58 * MB);       // 8 MB
  u16*  wqb   = (u16*)(ws + 66 * MB);       // 2 MB
  u16*  wkb   = (u16*)(ws + 68 * MB);       // 2 MB
  u16*  wvb   = (u16*)(ws + 70 * MB);       // 2 MB
  // scratch region phase 2 (aliases phase 1; valid once QKV GEMM completed):
  u16*  Opart = (u16*)(ws + 42 * MB);       // 16 MB (KSPLIT=2 bf16 partials)
  float2* mlp = (float2*)(ws + 58 * MB);    // 1 MB (aliases vb_, dead by then)
  // high-water 72 MB

  const int n8_t = MROWS * DM / 8;   // 524288 (== S*S/8 for the mask)
  const int n8_w = DM * DM / 8;      // 131072

  CastArgs ca;
  ca.s[0] = q;    ca.d[0] = qb_;
  ca.s[1] = k;    ca.d[1] = kb_;
  ca.s[2] = v;    ca.d[2] = vb_;
  ca.s[3] = mask; ca.d[3] = maskb;
  ca.s[4] = Wq;   ca.d[4] = wqb;
  ca.s[5] = Wk;   ca.d[5] = wkb;
  ca.s[6] = Wv;   ca.d[6] = wvb;
  ca.s[7] = Wo;   ca.d[7] = wob;
  cast_all_f32_bf16<<<dim3(1024, 8), 256, 0, stream>>>(ca, n8_t, n8_w);

  const float qscale = 0.125f * LOG2E;     // fold 1/sqrt(hd) and log2e into Q
  gemm_qkv<<<dim3(DM / 64, MROWS / 128, 3), 256, 0, stream>>>(
      qb_, kb_, vb_, wqb, wkb, wvb, bq, bk, bv, Qh, Kh, Vh, qscale);

  // flash: 1D grid (1024 blocks), XCD swizzle computed in-kernel
  flash_attn<<<dim3((S_LEN / 128) * (NHEAD * BATCH) * KSPLIT), 256, 0, stream>>>(
      Qh, Kh, Vh, maskb, Opart, mlp);
  fa_combine<<<NROWS * 16 / 256, 256, 0, stream>>>(Opart, mlp, Ob);

  gemm_out<<<dim3(DM / 64, MROWS / 128), 256, 0, stream>>>(Ob, wob, bo, out);
}